// Round 14
// baseline (97.369 us; speedup 1.0000x reference)
//
#include <hip/hip_runtime.h>
#include <hip/hip_fp16.h>

#define Bn   4
#define CINc 64
#define COUTc 64
#define Hn   128
#define Wn   128
#define HW   (Hn * Wn)
#define KKc  9
#define NOFF 18

typedef short bf16x8 __attribute__((ext_vector_type(8)));
typedef _Float16 hf16x8 __attribute__((ext_vector_type(8)));
typedef _Float16 hf16x2 __attribute__((ext_vector_type(2)));
typedef float f32x4  __attribute__((ext_vector_type(4)));

__device__ inline unsigned short f2h(float f) {    // RNE fp32 -> fp16 bits
    return __half_as_ushort(__float2half(f));
}

__device__ inline void dma16(const void* g, void* l) {
#if __has_builtin(__builtin_amdgcn_global_load_lds)
    __builtin_amdgcn_global_load_lds(
        (__attribute__((address_space(1))) void*)(g),
        (__attribute__((address_space(3))) void*)(l), 16, 0, 0);
#else
    *(uint4*)l = *(const uint4*)g;
#endif
}

// ---------------------------------------------------------------------------
// prep_all v21: identical structure to v20/v18, but ALL staged data is f16
// (xt, wob, wkb). f16 has 11-bit mantissa vs bf16's 8 -> precision improves;
// x ~ N(0,1) is far inside f16 range.
// ---------------------------------------------------------------------------
__global__ __launch_bounds__(256) void prep_all(
        const float* __restrict__ x, unsigned short* __restrict__ xt,
        const float* __restrict__ w_off, const float* __restrict__ w_def,
        unsigned short* __restrict__ wkb_sw, unsigned short* __restrict__ wob_sw) {
    int gb = blockIdx.x;
    int t  = threadIdx.x;
    if (gb < 1024) {
        __shared__ float s[64][65];
        int half = gb & 1;
        int h    = (gb >> 1) & 127;
        int b    = gb >> 8;
        int w0   = half * 64;

        const float* xb = x + (size_t)b * CINc * HW + (size_t)h * Wn + w0;
        int c0 = t >> 4, wq = (t & 15) * 4;
        #pragma unroll
        for (int i = 0; i < 4; ++i) {
            int c = c0 + i * 16;
            float4 v = *(const float4*)(xb + (size_t)c * HW + wq);
            s[c][wq]     = v.x;
            s[c][wq + 1] = v.y;
            s[c][wq + 2] = v.z;
            s[c][wq + 3] = v.w;
        }
        __syncthreads();

        int cpair = t & 31, pxg = t >> 5;
        unsigned* xtp = (unsigned*)xt;
        #pragma unroll
        for (int i = 0; i < 8; ++i) {
            int px = pxg * 8 + i;
            float v0 = s[cpair * 2][px], v1 = s[cpair * 2 + 1][px];
            unsigned d = (unsigned)f2h(v0) | ((unsigned)f2h(v1) << 16);
            xtp[(((size_t)(b * Hn + h) * Wn) + w0 + px) * 32 + cpair] = d;
        }
        return;
    }
    int idx = (gb - 1024) * 256 + t;
    if (idx < 36864) {
        int j = idx & 7, l = (idx >> 3) & 63, s = idx >> 9;
        int k = s >> 3, kc = (s >> 2) & 1, ot = s & 3;
        int l15 = l & 15, quad = l >> 4;
        int o = ot * 16 + l15, c = kc * 32 + quad * 8 + j;
        wkb_sw[idx] = f2h(w_def[((size_t)o * 64 + c) * 9 + k]);
    }
    int i2 = idx - 36864;
    if (i2 >= 0 && i2 < 18432) {
        int j = i2 & 7, l = (i2 >> 3) & 63, s = i2 >> 9;
        int tt = s >> 2, kc = (s >> 1) & 1, mt = s & 1;
        int l15 = l & 15, quad = l >> 4;
        int m = mt * 16 + l15, c = kc * 32 + quad * 8 + j;
        unsigned short v = 0;
        if (m < NOFF) v = f2h(w_off[((size_t)m * 64 + c) * 9 + tt]);
        wob_sw[i2] = v;
    }
}

// ---------------------------------------------------------------------------
// Fused deformable conv v21 = v20 (97.1us total, LDS-window gathers) with the
// datapath switched bf16 -> f16 and interp rebuilt on v_dot2_f32_f16:
//   per u32: 4 v_perm (corner-pair build) + 4 fdot2 (f32 acc) + 1 cvt_pkrtz
//   = 9 insts / ~4-deep chain, vs 13 insts / ~7-deep pk_fma chain. Weights
//   from phase1 are ALREADY half2 -> fdot2's B operand directly (TAP's 4
//   weight-unpack cvts deleted). MFMAs -> _f16 variants (same shape/rate).
// Round-9 ablation priced interp at ~16us of fused's 28 -> target ~10.
// Everything else (staging, swizzle, barriers, fallback): v20-verbatim.
// ---------------------------------------------------------------------------

#define AS_H2(u) __builtin_bit_cast(hf16x2, (unsigned)(u))

// f16 interp: BF.u[jd] = pack(dot2(pairs_lo), dot2(pairs_hi))
#define BFBUILD(C, kc, BF, W01H, W23H)                                       \
    do {                                                                     \
        const unsigned* t0 = (const unsigned*)&(C)[(kc) * 4 + 0];            \
        const unsigned* t1 = (const unsigned*)&(C)[(kc) * 4 + 1];            \
        const unsigned* b0 = (const unsigned*)&(C)[(kc) * 4 + 2];            \
        const unsigned* b1 = (const unsigned*)&(C)[(kc) * 4 + 3];            \
        _Pragma("unroll")                                                    \
        for (int jd = 0; jd < 4; ++jd) {                                     \
            unsigned plt = __builtin_amdgcn_perm(t1[jd], t0[jd], 0x05040100u);\
            unsigned pht = __builtin_amdgcn_perm(t1[jd], t0[jd], 0x07060302u);\
            unsigned plb = __builtin_amdgcn_perm(b1[jd], b0[jd], 0x05040100u);\
            unsigned phb = __builtin_amdgcn_perm(b1[jd], b0[jd], 0x07060302u);\
            float lo = __builtin_amdgcn_fdot2(AS_H2(plt), (W01H),            \
                       __builtin_amdgcn_fdot2(AS_H2(plb), (W23H), 0.f, false),\
                       false);                                               \
            float hi = __builtin_amdgcn_fdot2(AS_H2(pht), (W01H),            \
                       __builtin_amdgcn_fdot2(AS_H2(phb), (W23H), 0.f, false),\
                       false);                                               \
            (BF).u[jd] = __builtin_bit_cast(unsigned,                        \
                             __builtin_amdgcn_cvt_pkrtz(lo, hi));            \
        }                                                                    \
    } while (0)

#define TAP(k)                                                               \
    do {                                                                     \
        const uint4* C = R[(k) & 1];                                         \
        hf16x2 W01H = AS_H2(pw01[(k)]);                                      \
        hf16x2 W23H = AS_H2(pw23[(k)]);                                      \
        union { hf16x8 v; unsigned u[4]; } bfa, bfb;                         \
        BFBUILD(C, 0, bfa, W01H, W23H);                                      \
        BFBUILD(C, 1, bfb, W01H, W23H);                                      \
        _Pragma("unroll")                                                    \
        for (int ot = 0; ot < 4; ++ot) {                                     \
            hf16x8 af0 = s_wvh[(((k) * 2 + 0) * 4 + ot) * 64 + lane];        \
            acc[ot] = __builtin_amdgcn_mfma_f32_16x16x32_f16(                \
                af0, bfa.v, acc[ot], 0, 0, 0);                               \
            hf16x8 af1 = s_wvh[(((k) * 2 + 1) * 4 + ot) * 64 + lane];        \
            acc[ot] = __builtin_amdgcn_mfma_f32_16x16x32_f16(                \
                af1, bfb.v, acc[ot], 0, 0, 0);                               \
        }                                                                    \
    } while (0)

// global-path fetch (fallback when window exceeded) — bytes are bytes
#define FETCH_G(kk, st)                                              \
    do {                                                             \
        unsigned ad_ = ad[kk];                                       \
        unsigned xc_ = ad_ >> 16;                                    \
        unsigned at_ = (((ad_ & 255u) << 7) + xc_) << 6;             \
        unsigned ab_ = ((((ad_ >> 8) & 255u) << 7) + xc_) << 6;      \
        R[st][0] = *(const uint4*)(xtb + at_ + co0);                 \
        R[st][1] = *(const uint4*)(xtb + at_ + 64 + co0);            \
        R[st][2] = *(const uint4*)(xtb + ab_ + co0);                 \
        R[st][3] = *(const uint4*)(xtb + ab_ + 64 + co0);            \
        R[st][4] = *(const uint4*)(xtb + at_ + co1);                 \
        R[st][5] = *(const uint4*)(xtb + at_ + 64 + co1);            \
        R[st][6] = *(const uint4*)(xtb + ab_ + co1);                 \
        R[st][7] = *(const uint4*)(xtb + ab_ + 64 + co1);            \
    } while (0)

// LDS-window fetch (v20-verbatim)
#define FETCH_L(kk, st)                                              \
    do {                                                             \
        unsigned ad_ = ad[kk];                                       \
        int xc_ = (int)(ad_ >> 16);                                  \
        int r0_ = (int)(ad_ & 255u) - h + 2;                         \
        int r1_ = (int)((ad_ >> 8) & 255u) - h + 2;                  \
        int b00 = (r0_ * 128 + xc_) * 128;                           \
        int b10 = (r1_ * 128 + xc_) * 128;                           \
        int j0  = (quad ^ (xc_ & 7)) << 4;                           \
        int j1  = (quad ^ ((xc_ + 1) & 7)) << 4;                     \
        int j0b = ((4 + quad) ^ (xc_ & 7)) << 4;                     \
        int j1b = ((4 + quad) ^ ((xc_ + 1) & 7)) << 4;               \
        R[st][0] = *(const uint4*)(s_mem + b00 + j0);                \
        R[st][1] = *(const uint4*)(s_mem + b00 + 128 + j1);          \
        R[st][2] = *(const uint4*)(s_mem + b10 + j0);                \
        R[st][3] = *(const uint4*)(s_mem + b10 + 128 + j1);          \
        R[st][4] = *(const uint4*)(s_mem + b00 + j0b);               \
        R[st][5] = *(const uint4*)(s_mem + b00 + 128 + j1b);         \
        R[st][6] = *(const uint4*)(s_mem + b10 + j0b);               \
        R[st][7] = *(const uint4*)(s_mem + b10 + 128 + j1b);         \
    } while (0)

__global__ __launch_bounds__(512, 2) void fused_deform_v21(
        const unsigned short* __restrict__ xt,
        const unsigned short* __restrict__ wob_sw,
        const unsigned short* __restrict__ wkb_sw,
        const float* __restrict__ b_off, float* __restrict__ out) {
    extern __shared__ char s_mem[];                 // 155648 B dynamic
    const hf16x8* s_wvh = (const hf16x8*)(s_mem + 81920);

    int gid  = blockIdx.x;                  // 512
    int xcd  = gid & 7;
    int j    = gid >> 3;
    int hh   = j & 15;
    int b    = j >> 4;
    int h    = xcd * 16 + hh;
    int tid  = threadIdx.x;
    int lane = tid & 63;
    int wave = __builtin_amdgcn_readfirstlane(tid >> 6);   // 0..7
    int l15  = lane & 15;
    int quad = lane >> 4;
    int p    = wave * 16 + l15;

    const unsigned short* xtb = xt + (size_t)b * HW * 64;

    // ---- stage x-window (5 rows, swizzled content, linear dest) ----
    int xl = lane >> 3;
    int sl = lane & 7;
    #pragma unroll
    for (int i = 0; i < 10; ++i) {
        int slot = i * 8 + wave;            // 0..79
        int r  = slot >> 4;
        int g  = slot & 15;
        int y  = min(max(h - 2 + r, 0), Hn - 1);
        int xx = g * 8 + xl;
        int jj = sl ^ (xx & 7);
        dma16(xtb + ((size_t)y * Wn + xx) * 64 + jj * 8,
              s_mem + (size_t)r * 16384 + (size_t)g * 1024);
    }
    // ---- stage wob into weight region ----
    #pragma unroll
    for (int i = 0; i < 5; ++i) {
        int seg = i * 8 + wave;
        if (seg < 36)
            dma16((const uint4*)wob_sw + seg * 64 + lane,
                  s_mem + 81920 + (size_t)seg * 1024);
    }
    __syncthreads();                        // bar0: window + wob staged

    // ---- offset conv: 36 f16 MFMA, B-operand from LDS window ----
    f32x4 oa0 = (f32x4){0.f, 0.f, 0.f, 0.f};
    f32x4 oa1 = (f32x4){0.f, 0.f, 0.f, 0.f};
    #pragma unroll
    for (int t9 = 0; t9 < 9; ++t9) {
        int ty = t9 / 3, tx = t9 % 3;
        int y  = h - 1 + ty;
        int xg = p - 1 + tx;
        bool v = (y >= 0) && (y < Hn) && (xg >= 0) && (xg < Wn);
        unsigned m = v ? 0xFFFFFFFFu : 0u;
        int yc = min(max(y, 0), Hn - 1);
        int xc = min(max(xg, 0), Wn - 1);
        int r  = yc - h + 2;                // in [0,4]
        int base = (r * 128 + xc) * 128;
        uint4 L0 = *(const uint4*)(s_mem + base + ((quad ^ (xc & 7)) << 4));
        uint4 L1 = *(const uint4*)(s_mem + base + (((4 + quad) ^ (xc & 7)) << 4));
        #pragma unroll
        for (int kc = 0; kc < 2; ++kc) {
            union { hf16x8 v; uint4 u; } bf;
            bf.u = kc ? L1 : L0;
            bf.u.x &= m; bf.u.y &= m; bf.u.z &= m; bf.u.w &= m;
            hf16x8 a0 = s_wvh[((t9 * 2 + kc) * 2 + 0) * 64 + lane];
            hf16x8 a1 = s_wvh[((t9 * 2 + kc) * 2 + 1) * 64 + lane];
            oa0 = __builtin_amdgcn_mfma_f32_16x16x32_f16(a0, bf.v, oa0, 0, 0, 0);
            oa1 = __builtin_amdgcn_mfma_f32_16x16x32_f16(a1, bf.v, oa1, 0, 0, 0);
        }
    }

    // ---- phase-1 (v13 verbatim; weights already packed half2) ----
    unsigned my_ad[3]  = {0, 0, 0};
    unsigned my_w01[3] = {0, 0, 0};
    unsigned my_w23[3] = {0, 0, 0};
    auto phase1 = [&](int k, float dy, float dx, int slot) {
        float py  = (float)(h - 1 + k / 3) + dy;
        float pxf = (float)(p - 1 + k % 3) + dx;
        float y0f = floorf(py), x0f = floorf(pxf);
        float fy = py - y0f, fx = pxf - x0f;
        int y0 = (int)y0f, x0 = (int)x0f;
        bool vy0 = (y0 >= 0) & (y0 < Hn);
        bool vy1 = (y0 + 1 >= 0) & (y0 + 1 < Hn);
        bool vx0 = (x0 >= 0) & (x0 < Wn);
        bool vx1 = (x0 + 1 >= 0) & (x0 + 1 < Wn);
        float wy0 = vy0 ? 1.f - fy : 0.f;
        float wy1 = vy1 ? fy : 0.f;
        float wx0 = vx0 ? 1.f - fx : 0.f;
        float wx1 = vx1 ? fx : 0.f;
        int xc = min(max(x0, 0), Wn - 2);
        bool sel0 = (min(max(x0, 0), Wn - 1) != xc);
        bool sel1 = ((min(max(x0 + 1, 0), Wn - 1) - xc) == 1);
        float Wa = (sel0 ? 0.f : wx0) + (sel1 ? 0.f : wx1);
        float Wb = (sel0 ? wx0 : 0.f) + (sel1 ? wx1 : 0.f);
        int yc0 = min(max(y0, 0), Hn - 1), yc1 = min(max(y0 + 1, 0), Hn - 1);
        union { __half2 hv; unsigned u; } c01, c23;
        c01.hv = __floats2half2_rn(wy0 * Wa, wy0 * Wb);
        c23.hv = __floats2half2_rn(wy1 * Wa, wy1 * Wb);
        my_ad[slot]  = (unsigned)yc0 | ((unsigned)yc1 << 8) | ((unsigned)xc << 16);
        my_w01[slot] = c01.u;
        my_w23[slot] = c23.u;
    };
    int kb = quad * 2;
    phase1(kb,     oa0[0] + b_off[4 * quad],     oa0[1] + b_off[4 * quad + 1], 0);
    phase1(kb + 1, oa0[2] + b_off[4 * quad + 2], oa0[3] + b_off[4 * quad + 3], 1);
    if (quad == 0)
        phase1(8, oa1[0] + b_off[16], oa1[1] + b_off[17], 2);
    __syncthreads();                        // bar1: wob LDS reads done

    // ---- stage wkb (72 segs) over wob region; shuffles cover flight ----
    #pragma unroll
    for (int i = 0; i < 9; ++i) {
        int seg = i * 8 + wave;
        dma16((const uint4*)wkb_sw + (size_t)seg * 64 + lane,
              s_mem + 81920 + (size_t)seg * 1024);
    }

    unsigned ad[KKc], pw01[KKc], pw23[KKc];
    #pragma unroll
    for (int k = 0; k < KKc; ++k) {
        int src  = (k < 8) ? ((k >> 1) * 16 + l15) : l15;
        int slot = (k < 8) ? (k & 1) : 2;
        ad[k]   = (unsigned)__shfl((int)my_ad[slot],  src, 64);
        pw01[k] = (unsigned)__shfl((int)my_w01[slot], src, 64);
        pw23[k] = (unsigned)__shfl((int)my_w23[slot], src, 64);
    }
    __syncthreads();                        // bar2: wkb visible

    // ---- window test ----
    bool oow = false;
    #pragma unroll
    for (int k = 0; k < KKc; ++k) {
        int r0 = (int)(ad[k] & 255u) - h + 2;
        int r1 = (int)((ad[k] >> 8) & 255u) - h + 2;
        oow |= ((unsigned)r0 > 4u) | ((unsigned)r1 > 4u);
    }
    bool use_global = __any(oow);           // wave-uniform

    f32x4 acc[4];
    #pragma unroll
    for (int ot = 0; ot < 4; ++ot) acc[ot] = (f32x4){0.f, 0.f, 0.f, 0.f};

    uint4 R[2][8];
    int co0 = quad * 8, co1 = 32 + quad * 8;

    if (__builtin_expect(use_global, 0)) {
        FETCH_G(0, 0);
        FETCH_G(1, 1); TAP(0);
        FETCH_G(2, 0); TAP(1);
        FETCH_G(3, 1); TAP(2);
        FETCH_G(4, 0); TAP(3);
        FETCH_G(5, 1); TAP(4);
        FETCH_G(6, 0); TAP(5);
        FETCH_G(7, 1); TAP(6);
        FETCH_G(8, 0); TAP(7);
        TAP(8);
    } else {
        FETCH_L(0, 0);
        FETCH_L(1, 1); TAP(0);
        FETCH_L(2, 0); TAP(1);
        FETCH_L(3, 1); TAP(2);
        FETCH_L(4, 0); TAP(3);
        FETCH_L(5, 1); TAP(4);
        FETCH_L(6, 0); TAP(5);
        FETCH_L(7, 1); TAP(6);
        FETCH_L(8, 0); TAP(7);
        TAP(8);
    }

    #pragma unroll
    for (int ot = 0; ot < 4; ++ot)
        #pragma unroll
        for (int rr = 0; rr < 4; ++rr) {
            int o = ot * 16 + quad * 4 + rr;
            out[(((size_t)b * COUTc + o) * Hn + h) * Wn + p] = acc[ot][rr];
        }
}

// ---------------------------------------------------------------------------
extern "C" void kernel_launch(void* const* d_in, const int* in_sizes, int n_in,
                              void* d_out, int out_size, void* d_ws, size_t ws_size,
                              hipStream_t stream) {
    const float* x     = (const float*)d_in[0];
    const float* w_off = (const float*)d_in[1];
    const float* b_off = (const float*)d_in[2];
    const float* w_def = (const float*)d_in[3];
    float* out = (float*)d_out;

    char* ws = (char*)d_ws;
    unsigned short* xt = (unsigned short*)ws;                 // 8.39 MB
    ws += (size_t)Bn * HW * CINc * sizeof(unsigned short);
    unsigned short* wkb_sw = (unsigned short*)ws;             // 73728 B
    ws += 36864 * sizeof(unsigned short);
    unsigned short* wob_sw = (unsigned short*)ws;             // 36864 B

    static bool attr_set = false;
    if (!attr_set) {
        (void)hipFuncSetAttribute((const void*)fused_deform_v21,
                                  hipFuncAttributeMaxDynamicSharedMemorySize,
                                  155648);
        attr_set = true;
    }

    prep_all<<<1024 + 216, 256, 0, stream>>>(x, xt, w_off, w_def, wkb_sw, wob_sw);
    fused_deform_v21<<<Bn * Hn, 512, 155648, stream>>>(xt, wob_sw, wkb_sw, b_off, out);
}